// Round 5
// baseline (234.448 us; speedup 1.0000x reference)
//
#include <hip/hip_runtime.h>

// CrossCompressUnit: fp32 in / fp32 out (verified R3). B=262144, D=64.
// 16 lanes/row, float4 chunk per lane per tensor.
// R5: 4 chunks/thread (ILP-4: 8 independent streaming loads in flight
// before first use), weights amortized 4x, nontemporal streaming.
// Floor: 256 MiB @ ~6.8 TB/s (device-achieved per harness fills) ~= 38 us.

using f32x4 = __attribute__((ext_vector_type(4))) float;

constexpr int D_DIM = 64;
constexpr int B_ROWS = 262144;
constexpr int LANES_PER_ROW = 16;                       // 16 lanes x 4 elems = 64
constexpr int CHUNKS = B_ROWS * LANES_PER_ROW;          // float4 chunks per tensor
constexpr int PER_THREAD = 4;
constexpr int NTHREADS = CHUNKS / PER_THREAD;           // 1,048,576
constexpr int BLOCK = 256;

__device__ __forceinline__ float dot4(const f32x4 a, const f32x4 b) {
    return a[0]*b[0] + a[1]*b[1] + a[2]*b[2] + a[3]*b[3];
}

__global__ __launch_bounds__(BLOCK) void ccu_kernel(
    const f32x4* __restrict__ v,       // B*D fp32 as B*16 f32x4
    const f32x4* __restrict__ e,
    const f32x4* __restrict__ w_vv,    // D fp32 as 16 f32x4
    const f32x4* __restrict__ w_ev,
    const f32x4* __restrict__ w_ve,
    const f32x4* __restrict__ w_ee,
    const f32x4* __restrict__ bias_v,
    const f32x4* __restrict__ bias_e,
    f32x4* __restrict__ out_v,
    f32x4* __restrict__ out_e)
{
    const int tid = blockIdx.x * BLOCK + threadIdx.x;
    const int sub = tid & (LANES_PER_ROW - 1);   // chunk index within the row
    // NTHREADS % 16 == 0 -> all 4 streams share the same `sub` (same weights)

    // 8 independent streaming loads, all issued before first use
    f32x4 vs[PER_THREAD], es[PER_THREAD];
#pragma unroll
    for (int k = 0; k < PER_THREAD; ++k) {
        vs[k] = __builtin_nontemporal_load(&v[tid + k * NTHREADS]);
        es[k] = __builtin_nontemporal_load(&e[tid + k * NTHREADS]);
    }

    // weights + biases: 256B each, cached, amortized over 4 streams
    const f32x4 wvv = w_vv[sub];
    const f32x4 wev = w_ev[sub];
    const f32x4 wve = w_ve[sub];
    const f32x4 wee = w_ee[sub];
    const f32x4 bv  = bias_v[sub];
    const f32x4 be  = bias_e[sub];

    // per-lane partial dots for all 4 rows
    float s_vv[PER_THREAD], s_ev[PER_THREAD], s_ve[PER_THREAD], s_ee[PER_THREAD];
#pragma unroll
    for (int k = 0; k < PER_THREAD; ++k) {
        s_vv[k] = dot4(es[k], wvv);
        s_ev[k] = dot4(vs[k], wev);
        s_ve[k] = dot4(es[k], wve);
        s_ee[k] = dot4(vs[k], wee);
    }

    // butterfly across the 16 lanes of each row; 16 independent chains
#pragma unroll
    for (int m = 1; m < LANES_PER_ROW; m <<= 1) {
#pragma unroll
        for (int k = 0; k < PER_THREAD; ++k) {
            s_vv[k] += __shfl_xor(s_vv[k], m);
            s_ev[k] += __shfl_xor(s_ev[k], m);
            s_ve[k] += __shfl_xor(s_ve[k], m);
            s_ee[k] += __shfl_xor(s_ee[k], m);
        }
    }

    // v_out = v*(e.w_vv) + e*(v.w_ev) + bias_v
    // e_out = v*(e.w_ve) + e*(v.w_ee) + bias_e
#pragma unroll
    for (int k = 0; k < PER_THREAD; ++k) {
        f32x4 ov, oe;
#pragma unroll
        for (int j = 0; j < 4; ++j) {
            ov[j] = fmaf(vs[k][j], s_vv[k], fmaf(es[k][j], s_ev[k], bv[j]));
            oe[j] = fmaf(vs[k][j], s_ve[k], fmaf(es[k][j], s_ee[k], be[j]));
        }
        __builtin_nontemporal_store(ov, &out_v[tid + k * NTHREADS]);
        __builtin_nontemporal_store(oe, &out_e[tid + k * NTHREADS]);
    }
}

extern "C" void kernel_launch(void* const* d_in, const int* in_sizes, int n_in,
                              void* d_out, int out_size, void* d_ws, size_t ws_size,
                              hipStream_t stream) {
    const f32x4* v      = (const f32x4*)d_in[0];
    const f32x4* e      = (const f32x4*)d_in[1];
    const f32x4* w_vv   = (const f32x4*)d_in[2];
    const f32x4* w_ev   = (const f32x4*)d_in[3];
    const f32x4* w_ve   = (const f32x4*)d_in[4];
    const f32x4* w_ee   = (const f32x4*)d_in[5];
    const f32x4* bias_v = (const f32x4*)d_in[6];
    const f32x4* bias_e = (const f32x4*)d_in[7];

    f32x4* out_v = (f32x4*)d_out;                    // fp32 v_out
    f32x4* out_e = out_v + (size_t)CHUNKS;           // fp32 e_out

    ccu_kernel<<<NTHREADS / BLOCK, BLOCK, 0, stream>>>(
        v, e, w_vv, w_ev, w_ve, w_ee, bias_v, bias_e, out_v, out_e);
}